// Round 1
// baseline (412.006 us; speedup 1.0000x reference)
//
#include <hip/hip_runtime.h>
#include <hip/hip_bf16.h>

#define NATOMS 262144
#define NG     8192
#define FDIM   128
#define NELEM  118
#define EPS    1e-6f

// ---------------------------------------------------------------------------
// Kernel 1: T[idx][z] = softplus( dot(Wq[:,z], Wk[idx,:]) / sqrt(F) )
// 236 entries, one block.
// ---------------------------------------------------------------------------
__global__ void table_kernel(const float* __restrict__ Wq,
                             const float* __restrict__ Wk,
                             float* __restrict__ T) {
    int p = threadIdx.x;
    if (p < 2 * NELEM) {
        int idx = p / NELEM;
        int z   = p - idx * NELEM;
        float dot = 0.f;
        #pragma unroll 8
        for (int f = 0; f < FDIM; ++f)
            dot += Wq[f * NELEM + z] * Wk[idx * FDIM + f];
        float x = dot * 0.08838834764831843f;  // 1/sqrt(128)
        // stable softplus = max(x,0) + log1p(exp(-|x|))
        T[p] = fmaxf(x, 0.f) + log1pf(expf(-fabsf(x)));
    }
}

// ---------------------------------------------------------------------------
// Kernel 2: recover z[n] from the exact one-hot rows. Coalesced float4 sweep
// of the flat [N*E] array; nonzero element -> z[n] = e.
// ---------------------------------------------------------------------------
__global__ void zscan_kernel(const float4* __restrict__ onehot4,
                             int* __restrict__ z) {
    const int total4 = NATOMS * NELEM / 4;  // 7,733,248
    int i = blockIdx.x * blockDim.x + threadIdx.x;
    if (i >= total4) return;
    float4 v = onehot4[i];
    int base = i * 4;
    if (v.x > 0.5f) { int g = base + 0; int n = g / NELEM; z[n] = g - n * NELEM; }
    if (v.y > 0.5f) { int g = base + 1; int n = g / NELEM; z[n] = g - n * NELEM; }
    if (v.z > 0.5f) { int g = base + 2; int n = g / NELEM; z[n] = g - n * NELEM; }
    if (v.w > 0.5f) { int g = base + 3; int n = g / NELEM; z[n] = g - n * NELEM; }
}

// ---------------------------------------------------------------------------
// Kernel 3: y[n] = T[idx(g)][z[n]]; denom[g] += segment-sum(y).
// batch_segments is sorted -> wave-level segmented scan, boundary lanes do
// the (rare, ~12k total) atomics.
// ---------------------------------------------------------------------------
__global__ void ydenom_kernel(const int* __restrict__ seg,
                              const float* __restrict__ psi,
                              const float* __restrict__ T,
                              const int* __restrict__ z,
                              float* __restrict__ y_out,
                              float* __restrict__ denom) {
    int n = blockIdx.x * blockDim.x + threadIdx.x;
    int g = seg[n];
    float ps = psi[g];
    int idx = ps < 0.f ? 1 : 0;
    float yv = T[idx * NELEM + z[n]];
    y_out[n] = yv;

    int lane = threadIdx.x & 63;
    float val = yv;
    #pragma unroll
    for (int d = 1; d < 64; d <<= 1) {
        float o = __shfl_up(val, (unsigned)d, 64);
        int  go = __shfl_up(g,   (unsigned)d, 64);
        if (lane >= d && go == g) val += o;
    }
    int gn = __shfl_down(g, 1u, 64);
    if (lane == 63 || gn != g) atomicAdd(&denom[g], val);
}

// ---------------------------------------------------------------------------
// Kernel 4: per-atom MLP. 64 atoms/block, 256 threads.
//   v_att = att * Wv[idx];  h1 = silu(v_att) @ W1^T;  h2 = silu(h1) @ W2^T;
//   out = v_att + h2.
// LDS: actT[k][a] (transposed activations), wT[k][j] (transposed weights,
// padded stride 132), per-atom att/idx, Wv rows. 4x8 register blocking.
// ---------------------------------------------------------------------------
__launch_bounds__(256, 1)
__global__ void mlp_kernel(const int* __restrict__ seg,
                           const float* __restrict__ psi,
                           const float* __restrict__ y_ws,
                           const float* __restrict__ denom,
                           const float* __restrict__ Wv,
                           const float* __restrict__ W1,
                           const float* __restrict__ W2,
                           float* __restrict__ out) {
    __shared__ float att_s[64];
    __shared__ int   idx_s[64];
    __shared__ float wv_s[2 * FDIM];
    __shared__ float actT[FDIM][64];        // [k][atom]
    __shared__ float wT[FDIM][FDIM + 4];    // [k][j], padded

    int t   = threadIdx.x;
    int n0  = blockIdx.x * 64;

    if (t < 64) {
        int n = n0 + t;
        int g = seg[n];
        float ps = psi[g];
        idx_s[t] = ps < 0.f ? 1 : 0;
        att_s[t] = ps * y_ws[n] / (denom[g] + EPS);
    }
    wv_s[t] = Wv[t];  // 256 == 2*FDIM

    // load W1 transposed into wT: thread t covers row j=t>>1, half kh
    {
        int j  = t >> 1;
        int kh = (t & 1) * 64;
        const float4* src = (const float4*)&W1[j * FDIM + kh];
        #pragma unroll
        for (int q = 0; q < 16; ++q) {
            float4 w = src[q];
            int k = kh + q * 4;
            wT[k + 0][j] = w.x; wT[k + 1][j] = w.y;
            wT[k + 2][j] = w.z; wT[k + 3][j] = w.w;
        }
    }
    __syncthreads();

    // fill actT[f][a] = silu(att * wv[f])
    {
        int a  = t & 63;
        int fb = t >> 6;
        float att = att_s[a];
        const float* wv = &wv_s[idx_s[a] * FDIM];
        #pragma unroll 8
        for (int ff = 0; ff < 32; ++ff) {
            int f = fb * 32 + ff;
            float va = att * wv[f];
            actT[f][a] = va / (1.f + expf(-va));
        }
    }
    __syncthreads();

    int tx = t & 15, ty = t >> 4;
    int a0 = ty * 4, j0 = tx * 8;

    float acc[4][8];
    #pragma unroll
    for (int aa = 0; aa < 4; ++aa)
        #pragma unroll
        for (int jj = 0; jj < 8; ++jj) acc[aa][jj] = 0.f;

    #pragma unroll 8
    for (int k = 0; k < FDIM; ++k) {
        float4 a4 = *(const float4*)&actT[k][a0];
        float4 b0 = *(const float4*)&wT[k][j0];
        float4 b1 = *(const float4*)&wT[k][j0 + 4];
        float av[4] = {a4.x, a4.y, a4.z, a4.w};
        float bv[8] = {b0.x, b0.y, b0.z, b0.w, b1.x, b1.y, b1.z, b1.w};
        #pragma unroll
        for (int aa = 0; aa < 4; ++aa)
            #pragma unroll
            for (int jj = 0; jj < 8; ++jj)
                acc[aa][jj] = fmaf(av[aa], bv[jj], acc[aa][jj]);
    }
    __syncthreads();   // everyone done reading actT / wT

    // silu(h1) -> actT[j][a]; reload wT with W2
    #pragma unroll
    for (int aa = 0; aa < 4; ++aa)
        #pragma unroll
        for (int jj = 0; jj < 8; ++jj) {
            float h = acc[aa][jj];
            actT[j0 + jj][a0 + aa] = h / (1.f + expf(-h));
        }
    {
        int j  = t >> 1;
        int kh = (t & 1) * 64;
        const float4* src = (const float4*)&W2[j * FDIM + kh];
        #pragma unroll
        for (int q = 0; q < 16; ++q) {
            float4 w = src[q];
            int k = kh + q * 4;
            wT[k + 0][j] = w.x; wT[k + 1][j] = w.y;
            wT[k + 2][j] = w.z; wT[k + 3][j] = w.w;
        }
    }
    __syncthreads();

    float acc2[4][8];
    #pragma unroll
    for (int aa = 0; aa < 4; ++aa)
        #pragma unroll
        for (int jj = 0; jj < 8; ++jj) acc2[aa][jj] = 0.f;

    #pragma unroll 8
    for (int k = 0; k < FDIM; ++k) {
        float4 a4 = *(const float4*)&actT[k][a0];
        float4 b0 = *(const float4*)&wT[k][j0];
        float4 b1 = *(const float4*)&wT[k][j0 + 4];
        float av[4] = {a4.x, a4.y, a4.z, a4.w};
        float bv[8] = {b0.x, b0.y, b0.z, b0.w, b1.x, b1.y, b1.z, b1.w};
        #pragma unroll
        for (int aa = 0; aa < 4; ++aa)
            #pragma unroll
            for (int jj = 0; jj < 8; ++jj)
                acc2[aa][jj] = fmaf(av[aa], bv[jj], acc2[aa][jj]);
    }

    // out = v_att + h2
    #pragma unroll
    for (int aa = 0; aa < 4; ++aa) {
        int a = a0 + aa;
        float att = att_s[a];
        const float* wv = &wv_s[idx_s[a] * FDIM];
        float* orow = &out[(long)(n0 + a) * FDIM + j0];
        float4 o0, o1;
        o0.x = acc2[aa][0] + att * wv[j0 + 0];
        o0.y = acc2[aa][1] + att * wv[j0 + 1];
        o0.z = acc2[aa][2] + att * wv[j0 + 2];
        o0.w = acc2[aa][3] + att * wv[j0 + 3];
        o1.x = acc2[aa][4] + att * wv[j0 + 4];
        o1.y = acc2[aa][5] + att * wv[j0 + 5];
        o1.z = acc2[aa][6] + att * wv[j0 + 6];
        o1.w = acc2[aa][7] + att * wv[j0 + 7];
        *(float4*)&orow[0] = o0;
        *(float4*)&orow[4] = o1;
    }
}

// ---------------------------------------------------------------------------
extern "C" void kernel_launch(void* const* d_in, const int* in_sizes, int n_in,
                              void* d_out, int out_size, void* d_ws, size_t ws_size,
                              hipStream_t stream) {
    const float* onehot = (const float*)d_in[0];
    const float* psi    = (const float*)d_in[1];
    const float* Wq     = (const float*)d_in[2];
    const float* Wk     = (const float*)d_in[3];
    const float* Wv     = (const float*)d_in[4];
    const float* W1     = (const float*)d_in[5];
    const float* W2     = (const float*)d_in[6];
    const int*   seg    = (const int*)d_in[7];
    float*       out    = (float*)d_out;

    // workspace layout
    char* ws = (char*)d_ws;
    float* denom = (float*)ws;                       // G floats
    float* T     = (float*)(ws + NG * 4);            // 256 floats (236 used)
    int*   z     = (int*)(ws + NG * 4 + 1024);       // N ints
    float* y     = (float*)(ws + NG * 4 + 1024 + NATOMS * 4);  // N floats

    hipMemsetAsync(denom, 0, NG * sizeof(float), stream);

    table_kernel<<<1, 256, 0, stream>>>(Wq, Wk, T);

    {
        const int total4 = NATOMS * NELEM / 4;
        int blocks = (total4 + 255) / 256;
        zscan_kernel<<<blocks, 256, 0, stream>>>((const float4*)onehot, z);
    }

    ydenom_kernel<<<NATOMS / 256, 256, 0, stream>>>(seg, psi, T, z, y, denom);

    mlp_kernel<<<NATOMS / 64, 256, 0, stream>>>(seg, psi, y, denom, Wv, W1, W2, out);
}

// Round 2
// 123.975 us; speedup vs baseline: 3.3233x; 3.3233x over previous
//
#include <hip/hip_runtime.h>
#include <hip/hip_bf16.h>

#define NATOMS 262144
#define NG     8192
#define FDIM   128
#define NELEM  118
#define EPS    1e-6f
#define AST    152   // LDS activation row stride in bf16 elems: 304B rows, 16B-aligned, 2-way banks

typedef __attribute__((ext_vector_type(8))) short bf16x8;
typedef __attribute__((ext_vector_type(4))) float f32x4;

__device__ __forceinline__ unsigned short f2bf_rn(float x) {
    unsigned u = __float_as_uint(x);
    unsigned r = (u + 0x7FFFu + ((u >> 16) & 1u)) >> 16;
    return (unsigned short)r;
}
__device__ __forceinline__ float bf2f(unsigned short h) {
    return __uint_as_float((unsigned)h << 16);
}

// ---------------------------------------------------------------------------
// Kernel 1: T[idx][z] = softplus( dot(Wq[:,z], Wk[idx,:]) / sqrt(F) )
// ---------------------------------------------------------------------------
__global__ void table_kernel(const float* __restrict__ Wq,
                             const float* __restrict__ Wk,
                             float* __restrict__ T) {
    int p = threadIdx.x;
    if (p < 2 * NELEM) {
        int idx = p / NELEM;
        int z   = p - idx * NELEM;
        float dot = 0.f;
        #pragma unroll 8
        for (int f = 0; f < FDIM; ++f)
            dot += Wq[f * NELEM + z] * Wk[idx * FDIM + f];
        float x = dot * 0.08838834764831843f;  // 1/sqrt(128)
        T[p] = fmaxf(x, 0.f) + log1pf(expf(-fabsf(x)));
    }
}

// ---------------------------------------------------------------------------
// Kernel 1b: split W1,W2 into bf16 hi/lo. Whi/Wlo layout: [layer][j][k].
// ---------------------------------------------------------------------------
__global__ void wsplit_kernel(const float* __restrict__ W1,
                              const float* __restrict__ W2,
                              unsigned short* __restrict__ Whi,
                              unsigned short* __restrict__ Wlo) {
    int i = blockIdx.x * blockDim.x + threadIdx.x;  // 0..32767
    float x = (i < FDIM * FDIM) ? W1[i] : W2[i - FDIM * FDIM];
    unsigned short h = f2bf_rn(x);
    unsigned short l = f2bf_rn(x - bf2f(h));
    Whi[i] = h;
    Wlo[i] = l;
}

// ---------------------------------------------------------------------------
// Kernel 2: recover z[n] from the one-hot rows (coalesced float4 sweep).
// ---------------------------------------------------------------------------
__global__ void zscan_kernel(const float4* __restrict__ onehot4,
                             int* __restrict__ z) {
    const int total4 = NATOMS * NELEM / 4;
    int i = blockIdx.x * blockDim.x + threadIdx.x;
    if (i >= total4) return;
    float4 v = onehot4[i];
    int base = i * 4;
    if (v.x > 0.5f) { int g = base + 0; int n = g / NELEM; z[n] = g - n * NELEM; }
    if (v.y > 0.5f) { int g = base + 1; int n = g / NELEM; z[n] = g - n * NELEM; }
    if (v.z > 0.5f) { int g = base + 2; int n = g / NELEM; z[n] = g - n * NELEM; }
    if (v.w > 0.5f) { int g = base + 3; int n = g / NELEM; z[n] = g - n * NELEM; }
}

// ---------------------------------------------------------------------------
// Kernel 3: y[n] = T[idx(g)][z[n]]; denom[g] = segment_sum(y) via wave scan.
// ---------------------------------------------------------------------------
__global__ void ydenom_kernel(const int* __restrict__ seg,
                              const float* __restrict__ psi,
                              const float* __restrict__ T,
                              const int* __restrict__ z,
                              float* __restrict__ y_out,
                              float* __restrict__ denom) {
    int n = blockIdx.x * blockDim.x + threadIdx.x;
    int g = seg[n];
    float ps = psi[g];
    int idx = ps < 0.f ? 1 : 0;
    float yv = T[idx * NELEM + z[n]];
    y_out[n] = yv;

    int lane = threadIdx.x & 63;
    float val = yv;
    #pragma unroll
    for (int d = 1; d < 64; d <<= 1) {
        float o = __shfl_up(val, (unsigned)d, 64);
        int  go = __shfl_up(g,   (unsigned)d, 64);
        if (lane >= d && go == g) val += o;
    }
    int gn = __shfl_down(g, 1u, 64);
    if (lane == 63 || gn != g) atomicAdd(&denom[g], val);
}

// ---------------------------------------------------------------------------
// Kernel 4: MFMA MLP. 128 atoms/block, 4 waves; wave w owns cols [32w,32w+32)
// and all 128 rows. Split-bf16: 3 MFMA per fp32 tile-product.
// ---------------------------------------------------------------------------
__launch_bounds__(256, 2)
__global__ void mlp_kernel(const int* __restrict__ seg,
                           const float* __restrict__ psi,
                           const float* __restrict__ y_ws,
                           const float* __restrict__ denom,
                           const float* __restrict__ Wv,
                           const unsigned short* __restrict__ Whi,
                           const unsigned short* __restrict__ Wlo,
                           float* __restrict__ out) {
    __shared__ __align__(16) unsigned short Ahi[128 * AST];
    __shared__ __align__(16) unsigned short Alo[128 * AST];
    __shared__ float att_s[128];
    __shared__ int   idx_s[128];
    __shared__ float wv_s[2 * FDIM];

    int t    = threadIdx.x;
    int lane = t & 63;
    int w    = t >> 6;
    int n0   = blockIdx.x * 128;
    int jbase = w * 32;

    wv_s[t] = Wv[t];
    if (t < 128) {
        int n = n0 + t;
        int g = seg[n];
        float ps = psi[g];
        idx_s[t] = ps < 0.f ? 1 : 0;
        att_s[t] = ps * y_ws[n] / (denom[g] + EPS);
    }
    __syncthreads();

    // phase 1: act0[a][k] = silu(att*wv[idx][k]) -> split bf16 into LDS
    {
        int a  = t >> 1;
        int kh = (t & 1) * 64;
        float att = att_s[a];
        const float* wvp = &wv_s[idx_s[a] * FDIM];
        unsigned int* ph = (unsigned int*)&Ahi[a * AST + kh];
        unsigned int* pl = (unsigned int*)&Alo[a * AST + kh];
        #pragma unroll 8
        for (int kk = 0; kk < 64; kk += 2) {
            float v0 = att * wvp[kh + kk];
            float v1 = att * wvp[kh + kk + 1];
            float s0 = v0 / (1.f + __expf(-v0));
            float s1 = v1 / (1.f + __expf(-v1));
            unsigned short h0 = f2bf_rn(s0), h1 = f2bf_rn(s1);
            unsigned short l0 = f2bf_rn(s0 - bf2f(h0)), l1 = f2bf_rn(s1 - bf2f(h1));
            ph[kk >> 1] = (unsigned)h0 | ((unsigned)h1 << 16);
            pl[kk >> 1] = (unsigned)l0 | ((unsigned)l1 << 16);
        }
    }
    __syncthreads();

    int lrow = lane & 15;          // fragment row/col within tile
    int k0   = (lane >> 4) * 8;    // fragment k base

    f32x4 acc[8][2];
    bf16x8 bh[2][4], bl[2][4];

    #pragma unroll
    for (int L = 0; L < 2; ++L) {
        const unsigned short* WH = Whi + L * FDIM * FDIM;
        const unsigned short* WL = Wlo + L * FDIM * FDIM;
        // load B fragments (held in regs): B[k][j] = W[j][k] -> lane reads row j of W
        #pragma unroll
        for (int jt = 0; jt < 2; ++jt) {
            int j = jbase + jt * 16 + lrow;
            #pragma unroll
            for (int kt = 0; kt < 4; ++kt) {
                bh[jt][kt] = *(const bf16x8*)&WH[j * FDIM + kt * 32 + k0];
                bl[jt][kt] = *(const bf16x8*)&WL[j * FDIM + kt * 32 + k0];
            }
        }
        #pragma unroll
        for (int mt = 0; mt < 8; ++mt)
            #pragma unroll
            for (int jt = 0; jt < 2; ++jt)
                acc[mt][jt] = (f32x4){0.f, 0.f, 0.f, 0.f};

        #pragma unroll
        for (int kt = 0; kt < 4; ++kt) {
            #pragma unroll
            for (int mt = 0; mt < 8; ++mt) {
                int aoff = (mt * 16 + lrow) * AST + kt * 32 + k0;
                bf16x8 ah = *(const bf16x8*)&Ahi[aoff];
                bf16x8 al = *(const bf16x8*)&Alo[aoff];
                #pragma unroll
                for (int jt = 0; jt < 2; ++jt) {
                    acc[mt][jt] = __builtin_amdgcn_mfma_f32_16x16x32_bf16(ah, bh[jt][kt], acc[mt][jt], 0, 0, 0);
                    acc[mt][jt] = __builtin_amdgcn_mfma_f32_16x16x32_bf16(ah, bl[jt][kt], acc[mt][jt], 0, 0, 0);
                    acc[mt][jt] = __builtin_amdgcn_mfma_f32_16x16x32_bf16(al, bh[jt][kt], acc[mt][jt], 0, 0, 0);
                }
            }
        }

        if (L == 0) {
            // h1 -> silu -> split bf16 back into LDS (all k needed by all waves)
            __syncthreads();   // everyone finished reading layer-1 activations
            #pragma unroll
            for (int mt = 0; mt < 8; ++mt)
                #pragma unroll
                for (int jt = 0; jt < 2; ++jt)
                    #pragma unroll
                    for (int r = 0; r < 4; ++r) {
                        int row = mt * 16 + (lane >> 4) * 4 + r;
                        int col = jbase + jt * 16 + lrow;
                        float x = acc[mt][jt][r];
                        float s = x / (1.f + __expf(-x));
                        unsigned short h = f2bf_rn(s);
                        unsigned short l = f2bf_rn(s - bf2f(h));
                        Ahi[row * AST + col] = h;
                        Alo[row * AST + col] = l;
                    }
            __syncthreads();
        }
    }

    // epilogue: out = v_att + h2
    #pragma unroll
    for (int mt = 0; mt < 8; ++mt)
        #pragma unroll
        for (int jt = 0; jt < 2; ++jt)
            #pragma unroll
            for (int r = 0; r < 4; ++r) {
                int row = mt * 16 + (lane >> 4) * 4 + r;
                int col = jbase + jt * 16 + lrow;
                float vatt = att_s[row] * wv_s[idx_s[row] * FDIM + col];
                out[(long)(n0 + row) * FDIM + col] = acc[mt][jt][r] + vatt;
            }
}

// ---------------------------------------------------------------------------
extern "C" void kernel_launch(void* const* d_in, const int* in_sizes, int n_in,
                              void* d_out, int out_size, void* d_ws, size_t ws_size,
                              hipStream_t stream) {
    const float* onehot = (const float*)d_in[0];
    const float* psi    = (const float*)d_in[1];
    const float* Wq     = (const float*)d_in[2];
    const float* Wk     = (const float*)d_in[3];
    const float* Wv     = (const float*)d_in[4];
    const float* W1     = (const float*)d_in[5];
    const float* W2     = (const float*)d_in[6];
    const int*   seg    = (const int*)d_in[7];
    float*       out    = (float*)d_out;

    // workspace layout
    char* ws = (char*)d_ws;
    float*          denom = (float*)ws;                              // 8192 f
    float*          T     = (float*)(ws + 32768);                    // 256 f
    int*            z     = (int*)(ws + 33792);                      // N i32
    float*          y     = (float*)(ws + 33792 + NATOMS * 4);       // N f32
    unsigned short* Whi   = (unsigned short*)(ws + 33792 + NATOMS * 8);            // 2*128*128 u16
    unsigned short* Wlo   = (unsigned short*)(ws + 33792 + NATOMS * 8 + 65536);    // 2*128*128 u16

    hipMemsetAsync(denom, 0, NG * sizeof(float), stream);

    table_kernel<<<1, 256, 0, stream>>>(Wq, Wk, T);
    wsplit_kernel<<<(2 * FDIM * FDIM) / 256, 256, 0, stream>>>(W1, W2, Whi, Wlo);

    {
        const int total4 = NATOMS * NELEM / 4;
        int blocks = (total4 + 255) / 256;
        zscan_kernel<<<blocks, 256, 0, stream>>>((const float4*)onehot, z);
    }

    ydenom_kernel<<<NATOMS / 256, 256, 0, stream>>>(seg, psi, T, z, y, denom);

    mlp_kernel<<<NATOMS / 128, 256, 0, stream>>>(seg, psi, y, denom, Wv, Whi, Wlo, out);
}

// Round 3
// 119.562 us; speedup vs baseline: 3.4460x; 1.0369x over previous
//
#include <hip/hip_runtime.h>
#include <hip/hip_bf16.h>

#define NATOMS 262144
#define NG     8192
#define FDIM   128
#define NELEM  118
#define EPS    1e-6f
#define AST    152   // LDS activation row stride (bf16 elems): 304B rows, 16B aligned

typedef __attribute__((ext_vector_type(8))) short bf16x8;
typedef __attribute__((ext_vector_type(4))) float f32x4;

__device__ __forceinline__ unsigned short f2bf_rn(float x) {
    unsigned u = __float_as_uint(x);
    unsigned r = (u + 0x7FFFu + ((u >> 16) & 1u)) >> 16;
    return (unsigned short)r;
}
__device__ __forceinline__ float bf2f(unsigned short h) {
    return __uint_as_float((unsigned)h << 16);
}

// truncation-based hi/lo split of two floats -> packed u32 (hi pair, lo pair)
__device__ __forceinline__ void split2(float x0, float x1,
                                       unsigned& hpack, unsigned& lpack) {
    unsigned u0 = __float_as_uint(x0), u1 = __float_as_uint(x1);
    unsigned h0m = u0 & 0xFFFF0000u, h1m = u1 & 0xFFFF0000u;
    hpack = (u0 >> 16) | h1m;
    float l0 = x0 - __uint_as_float(h0m);
    float l1 = x1 - __uint_as_float(h1m);
    lpack = (__float_as_uint(l0) >> 16) | (__float_as_uint(l1) & 0xFFFF0000u);
}

// ---------------------------------------------------------------------------
// Kernel 1: T[idx][z] = softplus( dot(Wq[:,z], Wk[idx,:]) / sqrt(F) )
// ---------------------------------------------------------------------------
__global__ void table_kernel(const float* __restrict__ Wq,
                             const float* __restrict__ Wk,
                             float* __restrict__ T) {
    int p = threadIdx.x;
    if (p < 2 * NELEM) {
        int idx = p / NELEM;
        int z   = p - idx * NELEM;
        float dot = 0.f;
        #pragma unroll 8
        for (int f = 0; f < FDIM; ++f)
            dot += Wq[f * NELEM + z] * Wk[idx * FDIM + f];
        float x = dot * 0.08838834764831843f;  // 1/sqrt(128)
        T[p] = fmaxf(x, 0.f) + log1pf(expf(-fabsf(x)));
    }
}

// ---------------------------------------------------------------------------
// Kernel 1b: split W1,W2 into bf16 hi/lo (round-nearest; runs once, tiny).
// ---------------------------------------------------------------------------
__global__ void wsplit_kernel(const float* __restrict__ W1,
                              const float* __restrict__ W2,
                              unsigned short* __restrict__ Whi,
                              unsigned short* __restrict__ Wlo) {
    int i = blockIdx.x * blockDim.x + threadIdx.x;  // 0..32767
    float x = (i < FDIM * FDIM) ? W1[i] : W2[i - FDIM * FDIM];
    unsigned short h = f2bf_rn(x);
    unsigned short l = f2bf_rn(x - bf2f(h));
    Whi[i] = h;
    Wlo[i] = l;
}

// ---------------------------------------------------------------------------
// Kernel 2: recover z[n] from the one-hot rows (coalesced float4 sweep).
// ---------------------------------------------------------------------------
__global__ void zscan_kernel(const float4* __restrict__ onehot4,
                             int* __restrict__ z) {
    const int total4 = NATOMS * NELEM / 4;
    int i = blockIdx.x * blockDim.x + threadIdx.x;
    if (i >= total4) return;
    float4 v = onehot4[i];
    int base = i * 4;
    if (v.x > 0.5f) { int g = base + 0; int n = g / NELEM; z[n] = g - n * NELEM; }
    if (v.y > 0.5f) { int g = base + 1; int n = g / NELEM; z[n] = g - n * NELEM; }
    if (v.z > 0.5f) { int g = base + 2; int n = g / NELEM; z[n] = g - n * NELEM; }
    if (v.w > 0.5f) { int g = base + 3; int n = g / NELEM; z[n] = g - n * NELEM; }
}

// ---------------------------------------------------------------------------
// Kernel 3: y[n] = T[idx(g)][z[n]]; denom[g] = segment_sum(y) via wave scan.
// ---------------------------------------------------------------------------
__global__ void ydenom_kernel(const int* __restrict__ seg,
                              const float* __restrict__ psi,
                              const float* __restrict__ T,
                              const int* __restrict__ z,
                              float* __restrict__ y_out,
                              float* __restrict__ denom) {
    int n = blockIdx.x * blockDim.x + threadIdx.x;
    int g = seg[n];
    float ps = psi[g];
    int idx = ps < 0.f ? 1 : 0;
    float yv = T[idx * NELEM + z[n]];
    y_out[n] = yv;

    int lane = threadIdx.x & 63;
    float val = yv;
    #pragma unroll
    for (int d = 1; d < 64; d <<= 1) {
        float o = __shfl_up(val, (unsigned)d, 64);
        int  go = __shfl_up(g,   (unsigned)d, 64);
        if (lane >= d && go == g) val += o;
    }
    int gn = __shfl_down(g, 1u, 64);
    if (lane == 63 || gn != g) atomicAdd(&denom[g], val);
}

// ---------------------------------------------------------------------------
// Kernel 4: MFMA MLP. 128 atoms/block, 512 threads = 8 waves in a 2x4 grid.
// Wave (wr,wc) owns rows [64*wr, 64*wr+64) x cols [32*wc, 32*wc+32).
// Split-bf16 (3 MFMA per fp32 product). LDS 79.9KB -> 2 blocks/CU,
// 4 waves/SIMD.
// ---------------------------------------------------------------------------
__launch_bounds__(512, 4)
__global__ void mlp_kernel(const int* __restrict__ seg,
                           const float* __restrict__ psi,
                           const float* __restrict__ y_ws,
                           const float* __restrict__ denom,
                           const float* __restrict__ Wv,
                           const unsigned short* __restrict__ Whi,
                           const unsigned short* __restrict__ Wlo,
                           float* __restrict__ out) {
    __shared__ __align__(16) unsigned short Ahi[128 * AST];
    __shared__ __align__(16) unsigned short Alo[128 * AST];
    __shared__ float att_s[128];
    __shared__ int   idx_s[128];
    __shared__ float wv_s[2 * FDIM];

    int t    = threadIdx.x;
    int lane = t & 63;
    int w    = t >> 6;
    int wr   = w >> 2;
    int wc   = w & 3;
    int n0   = blockIdx.x * 128;
    int rbase = wr * 64;
    int jbase = wc * 32;

    if (t < 256) wv_s[t] = Wv[t];
    if (t >= 256 && t < 384) {
        int a = t - 256;
        int n = n0 + a;
        int g = seg[n];
        float ps = psi[g];
        idx_s[a] = ps < 0.f ? 1 : 0;
        att_s[a] = ps * y_ws[n] / (denom[g] + EPS);
    }
    __syncthreads();

    // phase 1: act0[a][k] = silu(att*wv[idx][k]) -> split bf16 into LDS
    {
        int a  = t >> 2;
        int kq = (t & 3) * 32;
        float att = att_s[a];
        const float* wvp = &wv_s[idx_s[a] * FDIM + kq];
        unsigned int* ph = (unsigned int*)&Ahi[a * AST + kq];
        unsigned int* pl = (unsigned int*)&Alo[a * AST + kq];
        #pragma unroll
        for (int kk = 0; kk < 32; kk += 2) {
            float v0 = att * wvp[kk];
            float v1 = att * wvp[kk + 1];
            float s0 = v0 / (1.f + __expf(-v0));
            float s1 = v1 / (1.f + __expf(-v1));
            unsigned hp, lp;
            split2(s0, s1, hp, lp);
            ph[kk >> 1] = hp;
            pl[kk >> 1] = lp;
        }
    }
    __syncthreads();

    int lrow = lane & 15;          // fragment row/col within a 16x16 tile
    int k0   = (lane >> 4) * 8;    // fragment k base

    f32x4 acc[4][2];

    #pragma unroll
    for (int L = 0; L < 2; ++L) {
        const unsigned short* WH = Whi + L * FDIM * FDIM;
        const unsigned short* WL = Wlo + L * FDIM * FDIM;

        #pragma unroll
        for (int mt = 0; mt < 4; ++mt)
            #pragma unroll
            for (int jt = 0; jt < 2; ++jt)
                acc[mt][jt] = (f32x4){0.f, 0.f, 0.f, 0.f};

        #pragma unroll 1
        for (int kt = 0; kt < 4; ++kt) {
            bf16x8 bh[2], bl[2];
            #pragma unroll
            for (int jt = 0; jt < 2; ++jt) {
                int j = jbase + jt * 16 + lrow;
                bh[jt] = *(const bf16x8*)&WH[j * FDIM + kt * 32 + k0];
                bl[jt] = *(const bf16x8*)&WL[j * FDIM + kt * 32 + k0];
            }
            #pragma unroll
            for (int mt = 0; mt < 4; ++mt) {
                int aoff = (rbase + mt * 16 + lrow) * AST + kt * 32 + k0;
                bf16x8 ah = *(const bf16x8*)&Ahi[aoff];
                bf16x8 al = *(const bf16x8*)&Alo[aoff];
                #pragma unroll
                for (int jt = 0; jt < 2; ++jt) {
                    acc[mt][jt] = __builtin_amdgcn_mfma_f32_16x16x32_bf16(ah, bh[jt], acc[mt][jt], 0, 0, 0);
                    acc[mt][jt] = __builtin_amdgcn_mfma_f32_16x16x32_bf16(ah, bl[jt], acc[mt][jt], 0, 0, 0);
                    acc[mt][jt] = __builtin_amdgcn_mfma_f32_16x16x32_bf16(al, bh[jt], acc[mt][jt], 0, 0, 0);
                }
            }
        }

        if (L == 0) {
            __syncthreads();   // all waves done reading layer-0 activations
            #pragma unroll
            for (int mt = 0; mt < 4; ++mt)
                #pragma unroll
                for (int jt = 0; jt < 2; ++jt)
                    #pragma unroll
                    for (int r = 0; r < 4; ++r) {
                        int row = rbase + mt * 16 + (lane >> 4) * 4 + r;
                        int col = jbase + jt * 16 + lrow;
                        float x = acc[mt][jt][r];
                        float s = x / (1.f + __expf(-x));
                        unsigned u = __float_as_uint(s);
                        unsigned hm = u & 0xFFFF0000u;
                        float l = s - __uint_as_float(hm);
                        Ahi[row * AST + col] = (unsigned short)(u >> 16);
                        Alo[row * AST + col] = (unsigned short)(__float_as_uint(l) >> 16);
                    }
            __syncthreads();
        }
    }

    // epilogue: out = v_att + h2
    #pragma unroll
    for (int mt = 0; mt < 4; ++mt)
        #pragma unroll
        for (int jt = 0; jt < 2; ++jt)
            #pragma unroll
            for (int r = 0; r < 4; ++r) {
                int row = rbase + mt * 16 + (lane >> 4) * 4 + r;
                int col = jbase + jt * 16 + lrow;
                float vatt = att_s[row] * wv_s[idx_s[row] * FDIM + col];
                out[(long)(n0 + row) * FDIM + col] = acc[mt][jt][r] + vatt;
            }
}

// ---------------------------------------------------------------------------
extern "C" void kernel_launch(void* const* d_in, const int* in_sizes, int n_in,
                              void* d_out, int out_size, void* d_ws, size_t ws_size,
                              hipStream_t stream) {
    const float* onehot = (const float*)d_in[0];
    const float* psi    = (const float*)d_in[1];
    const float* Wq     = (const float*)d_in[2];
    const float* Wk     = (const float*)d_in[3];
    const float* Wv     = (const float*)d_in[4];
    const float* W1     = (const float*)d_in[5];
    const float* W2     = (const float*)d_in[6];
    const int*   seg    = (const int*)d_in[7];
    float*       out    = (float*)d_out;

    // workspace layout
    char* ws = (char*)d_ws;
    float*          denom = (float*)ws;                              // 8192 f
    float*          T     = (float*)(ws + 32768);                    // 256 f
    int*            z     = (int*)(ws + 33792);                      // N i32
    float*          y     = (float*)(ws + 33792 + NATOMS * 4);       // N f32
    unsigned short* Whi   = (unsigned short*)(ws + 33792 + NATOMS * 8);            // 2*128*128 u16
    unsigned short* Wlo   = (unsigned short*)(ws + 33792 + NATOMS * 8 + 65536);    // 2*128*128 u16

    hipMemsetAsync(denom, 0, NG * sizeof(float), stream);

    table_kernel<<<1, 256, 0, stream>>>(Wq, Wk, T);
    wsplit_kernel<<<(2 * FDIM * FDIM) / 256, 256, 0, stream>>>(W1, W2, Whi, Wlo);

    {
        const int total4 = NATOMS * NELEM / 4;
        int blocks = (total4 + 255) / 256;
        zscan_kernel<<<blocks, 256, 0, stream>>>((const float4*)onehot, z);
    }

    ydenom_kernel<<<NATOMS / 256, 256, 0, stream>>>(seg, psi, T, z, y, denom);

    mlp_kernel<<<NATOMS / 128, 512, 0, stream>>>(seg, psi, y, denom, Wv, Whi, Wlo, out);
}